// Round 17
// baseline (781.894 us; speedup 1.0000x reference)
//
#include <hip/hip_runtime.h>
#include <math.h>

#define NQ   300
#define DMODEL 256
#define NHEAD 8
#define HDIM 32
#define BB   2
#define NKV  4096
#define RPEH 512
#define NLAYER 6
#define ATTN_SCALE 0.17677669529663687f  // 1/sqrt(32)

typedef short short8 __attribute__((ext_vector_type(8)));
typedef float f32x4 __attribute__((ext_vector_type(4)));
typedef unsigned short ushort_t;

__device__ __forceinline__ short f2bf(float f) {
    union { float fv; unsigned u; } v; v.fv = f;
    unsigned r = v.u + 0x7FFFu + ((v.u >> 16) & 1u);   // RNE
    return (short)(r >> 16);
}
__device__ __forceinline__ float bf2f(ushort_t u) {
    union { unsigned u; float f; } v; v.u = ((unsigned)u) << 16;
    return v.f;
}
__device__ __forceinline__ short8 pack_bf8(float4 x, float4 y) {
    short8 v;
    v[0] = f2bf(x.x); v[1] = f2bf(x.y); v[2] = f2bf(x.z); v[3] = f2bf(x.w);
    v[4] = f2bf(y.x); v[5] = f2bf(y.y); v[6] = f2bf(y.z); v[7] = f2bf(y.w);
    return v;
}

// ---------------------------------------------------------------------------
// prep: kvb16 = bf16(src+spe); srcb16 = bf16(src); out init (fp32+bf16+q16);
// box corners.
// ---------------------------------------------------------------------------
__global__ __launch_bounds__(256) void prep_kernel(
    const float* __restrict__ src, const float* __restrict__ spe,
    const float* __restrict__ tgt, const float* __restrict__ qpos,
    const float* __restrict__ refp,
    ushort_t* __restrict__ kvb16, ushort_t* __restrict__ srcb16,
    float* __restrict__ outb, ushort_t* __restrict__ ob16,
    ushort_t* __restrict__ oq16,
    float* __restrict__ boxx, float* __restrict__ boxy)
{
    int i = blockIdx.x * 256 + threadIdx.x;
    if (i < BB * NKV * DMODEL) {
        float s = src[i];
        kvb16[i]  = (ushort_t)f2bf(s + spe[i]);
        srcb16[i] = (ushort_t)f2bf(s);
    }
    if (i < BB * NQ * DMODEL) {
        float tv = tgt[i];
        outb[i] = tv;
        ob16[i] = (ushort_t)f2bf(tv);
        oq16[i] = (ushort_t)f2bf(tv + qpos[i]);
    }
    if (i < BB * NQ) {
        float cx = refp[i * 4 + 0], cy = refp[i * 4 + 1];
        float w  = refp[i * 4 + 2], h  = refp[i * 4 + 3];
        boxx[i * 2 + 0] = cx - 0.5f * w;
        boxx[i * 2 + 1] = cx + 0.5f * w;
        boxy[i * 2 + 0] = cy - 0.5f * h;
        boxy[i * 2 + 1] = cy + 0.5f * h;
    }
}

// ---------------------------------------------------------------------------
// wconv: convert all GEMM weights fp32 -> bf16 into one ws region.
// ---------------------------------------------------------------------------
__global__ __launch_bounds__(256) void wconv_kernel(
    const float* __restrict__ sain, const float* __restrict__ saout,
    const float* __restrict__ caq, const float* __restrict__ cak,
    const float* __restrict__ cav, const float* __restrict__ cap,
    const float* __restrict__ f1, const float* __restrict__ f2,
    ushort_t* __restrict__ dst)
{
    size_t i = ((size_t)blockIdx.x * 256 + threadIdx.x) * 8;
    if (i >= 6291456) return;
    const float* s; size_t off;
    if      (i < 1179648) { s = sain;  off = i; }
    else if (i < 1572864) { s = saout; off = i - 1179648; }
    else if (i < 1966080) { s = caq;   off = i - 1572864; }
    else if (i < 2359296) { s = cak;   off = i - 1966080; }
    else if (i < 2752512) { s = cav;   off = i - 2359296; }
    else if (i < 3145728) { s = cap;   off = i - 2752512; }
    else if (i < 4718592) { s = f1;    off = i - 3145728; }
    else                  { s = f2;    off = i - 4718592; }
    float4 x = *(const float4*)&s[off];
    float4 y = *(const float4*)&s[off + 4];
    *(short8*)&dst[i] = pack_bf8(x, y);
}

// ---------------------------------------------------------------------------
// kv_mega v6: reg-cached A + coalesced-store epilogue + XCD swizzle +
// layer-half split. 2048 blocks (8/CU, full wave slots); block does 3 layers.
// Decomposition keeps all blocks sharing an A-panel on one XCD.
// ---------------------------------------------------------------------------
__global__ __launch_bounds__(256) void kv_mega(
    const ushort_t* __restrict__ kvb16, const ushort_t* __restrict__ srcb16,
    const ushort_t* __restrict__ Wk, const ushort_t* __restrict__ Wv,
    const float* __restrict__ kbias, const float* __restrict__ vbias,
    ushort_t* __restrict__ Kcb, ushort_t* __restrict__ Vcb)
{
    __shared__ short C_s[64][72];
    const int t = threadIdx.x;
    const int lane = t & 63, w = t >> 6;
    const int wr = w >> 1, wc = w & 1;
    const int l15 = lane & 15, lhi8 = (lane >> 4) * 8;

    // 2048 = 8 xcd x (4 n x 2 sel x 2 lhalf x 16 m_local)
    const int wgid = blockIdx.x;
    const int xcd  = wgid & 7;
    const int idx  = wgid >> 3;            // 0..255
    const int n0   = (idx & 3) * 64;
    const int sel  = (idx >> 2) & 1;
    const int l0   = ((idx >> 3) & 1) * 3;
    const int m0   = (xcd * 16 + (idx >> 4)) * 64;

    const ushort_t* A  = sel ? srcb16 : kvb16;
    const ushort_t* Wb = sel ? Wv : Wk;
    const float* bb    = sel ? vbias : kbias;
    ushort_t* Cb       = sel ? Vcb : Kcb;

    // load this lane's two A-row slices into registers (64 VGPRs)
    const ushort_t* ap0 = &A[(size_t)(m0 + wr * 32 + l15) * 256 + lhi8];
    const ushort_t* ap1 = ap0 + 16 * 256;
    short8 a0r[8], a1r[8];
#pragma unroll
    for (int k = 0; k < 8; ++k) {
        a0r[k] = *(const short8*)(ap0 + k * 32);
        a1r[k] = *(const short8*)(ap1 + k * 32);
    }

    const int rowl = wr * 32 + (lane >> 4) * 4;

    for (int l = l0; l < l0 + 3; ++l) {
        const ushort_t* wp0 = &Wb[(size_t)l * 65536 + (size_t)(n0 + wc * 32 + l15) * 256 + lhi8];
        const ushort_t* wp1 = wp0 + 16 * 256;
        f32x4 acc[2][2];
#pragma unroll
        for (int i = 0; i < 2; ++i)
#pragma unroll
            for (int j = 0; j < 2; ++j)
#pragma unroll
                for (int r = 0; r < 4; ++r) acc[i][j][r] = 0.f;
#pragma unroll
        for (int k = 0; k < 8; ++k) {
            short8 b0 = *(const short8*)(wp0 + k * 32);
            short8 b1 = *(const short8*)(wp1 + k * 32);
            acc[0][0] = __builtin_amdgcn_mfma_f32_16x16x32_bf16(a0r[k], b0, acc[0][0], 0, 0, 0);
            acc[0][1] = __builtin_amdgcn_mfma_f32_16x16x32_bf16(a0r[k], b1, acc[0][1], 0, 0, 0);
            acc[1][0] = __builtin_amdgcn_mfma_f32_16x16x32_bf16(a1r[k], b0, acc[1][0], 0, 0, 0);
            acc[1][1] = __builtin_amdgcn_mfma_f32_16x16x32_bf16(a1r[k], b1, acc[1][1], 0, 0, 0);
        }

        const float* bl = bb + l * 256;
        __syncthreads();   // previous layer's store-pass reads complete
#pragma unroll
        for (int ni = 0; ni < 2; ++ni) {
            int cl = wc * 32 + ni * 16 + l15;
            float bv = bl[n0 + cl];
#pragma unroll
            for (int mi = 0; mi < 2; ++mi)
#pragma unroll
                for (int r = 0; r < 4; ++r)
                    C_s[rowl + mi * 16 + r][cl] = f2bf(acc[mi][ni][r] + bv);
        }
        __syncthreads();

        ushort_t* C = Cb + (size_t)l * (BB * NKV * DMODEL);
#pragma unroll
        for (int p = 0; p < 2; ++p) {
            int e = p * 256 + t;
            int row = e >> 3, c8 = (e & 7) * 8;
            *(short8*)&C[(size_t)(m0 + row) * 256 + n0 + c8] =
                *(short8*)&C_s[row][c8];
        }
    }
}

// ---------------------------------------------------------------------------
// gemm_direct: LDS-free bf16 GEMM.
// ---------------------------------------------------------------------------
template<int OUT_BF16, int RELU>
__global__ __launch_bounds__(256) void gemm_direct(
    const ushort_t* __restrict__ A1, const ushort_t* __restrict__ A2, int plimit,
    int lda, const ushort_t* __restrict__ W, const float* __restrict__ bias,
    void* __restrict__ Cv, int ldc, int M, int K, float scale, int slimit)
{
    const int t = threadIdx.x;
    const int lane = t & 63, w = t >> 6;
    const int wr = w >> 1, wc = w & 1;
    const int l15 = lane & 15, lhi8 = (lane >> 4) * 8;
    const int m0 = blockIdx.y * 64, n0 = blockIdx.x * 64;
    const ushort_t* A = (n0 < plimit) ? A1 : A2;

    int r0 = m0 + wr * 32 + l15;      if (r0 > M - 1) r0 = M - 1;
    int r1 = m0 + wr * 32 + 16 + l15; if (r1 > M - 1) r1 = M - 1;
    const ushort_t* ap0 = &A[(size_t)r0 * lda + lhi8];
    const ushort_t* ap1 = &A[(size_t)r1 * lda + lhi8];
    const ushort_t* wp0 = &W[(size_t)(n0 + wc * 32 + l15) * K + lhi8];
    const ushort_t* wp1 = wp0 + (size_t)16 * K;

    f32x4 acc[2][2];
#pragma unroll
    for (int i = 0; i < 2; ++i)
#pragma unroll
        for (int j = 0; j < 2; ++j)
#pragma unroll
            for (int r = 0; r < 4; ++r) acc[i][j][r] = 0.f;

    for (int k0 = 0; k0 < K; k0 += 32) {
        short8 a0 = *(const short8*)(ap0 + k0);
        short8 a1 = *(const short8*)(ap1 + k0);
        short8 b0 = *(const short8*)(wp0 + k0);
        short8 b1 = *(const short8*)(wp1 + k0);
        acc[0][0] = __builtin_amdgcn_mfma_f32_16x16x32_bf16(a0, b0, acc[0][0], 0, 0, 0);
        acc[0][1] = __builtin_amdgcn_mfma_f32_16x16x32_bf16(a0, b1, acc[0][1], 0, 0, 0);
        acc[1][0] = __builtin_amdgcn_mfma_f32_16x16x32_bf16(a1, b0, acc[1][0], 0, 0, 0);
        acc[1][1] = __builtin_amdgcn_mfma_f32_16x16x32_bf16(a1, b1, acc[1][1], 0, 0, 0);
    }

    const int rowb = m0 + wr * 32 + (lane >> 4) * 4;
    const int colb = n0 + wc * 32 + l15;
#pragma unroll
    for (int ni = 0; ni < 2; ++ni) {
        int col = colb + ni * 16;
        float bv = bias[col];
#pragma unroll
        for (int mi = 0; mi < 2; ++mi)
#pragma unroll
            for (int r = 0; r < 4; ++r) {
                int row = rowb + mi * 16 + r;
                if (row < M) {
                    float v = acc[mi][ni][r] + bv;
                    if (col < slimit) v *= scale;
                    if (RELU) v = fmaxf(v, 0.f);
                    if (OUT_BF16)
                        ((ushort_t*)Cv)[(size_t)row * ldc + col] = (ushort_t)f2bf(v);
                    else
                        ((float*)Cv)[(size_t)row * ldc + col] = v;
                }
            }
    }
}

// ---------------------------------------------------------------------------
// LayerNorm(out + t) -> outb fp32, ob16 bf16, oq16 = bf16(out + qpos)
// ---------------------------------------------------------------------------
__global__ __launch_bounds__(256) void ln_residual(
    float* __restrict__ out, const float* __restrict__ tt,
    const float* __restrict__ qpos,
    const float* __restrict__ w, const float* __restrict__ b,
    ushort_t* __restrict__ ob16, ushort_t* __restrict__ oq16, int rows)
{
    const int wid = threadIdx.x >> 6, lane = threadIdx.x & 63;
    const int row = blockIdx.x * 4 + wid;
    if (row >= rows) return;
    const float* orow = out + row * DMODEL;
    const float* trow = tt + row * DMODEL;
    float x[4];
#pragma unroll
    for (int i = 0; i < 4; ++i) x[i] = orow[lane + 64 * i] + trow[lane + 64 * i];
    float s = x[0] + x[1] + x[2] + x[3];
#pragma unroll
    for (int mask = 1; mask < 64; mask <<= 1) s += __shfl_xor(s, mask);
    float mean = s * (1.f / 256.f);
    float vs = 0.f;
#pragma unroll
    for (int i = 0; i < 4; ++i) { float d = x[i] - mean; vs += d * d; }
#pragma unroll
    for (int mask = 1; mask < 64; mask <<= 1) vs += __shfl_xor(vs, mask);
    float r = rsqrtf(vs * (1.f / 256.f) + 1e-5f);
    float* orw = out + row * DMODEL;
#pragma unroll
    for (int i = 0; i < 4; ++i) {
        int c = lane + 64 * i;
        float val = (x[i] - mean) * r * w[c] + b[c];
        orw[c] = val;
        ob16[row * DMODEL + c] = (ushort_t)f2bf(val);
        oq16[row * DMODEL + c] = (ushort_t)f2bf(val + qpos[row * DMODEL + c]);
    }
}

// ---------------------------------------------------------------------------
// RPE MLP via MFMA. Block = one (bq, axis, layer); grid (600, 2, 6).
// ---------------------------------------------------------------------------
__global__ __launch_bounds__(256) void rpe_all(
    const float* __restrict__ boxx, const float* __restrict__ boxy,
    const float* __restrict__ cpb1_w1, const float* __restrict__ cpb1_b1,
    const float* __restrict__ cpb1_w2,
    const float* __restrict__ cpb2_w1, const float* __restrict__ cpb2_b1,
    const float* __restrict__ cpb2_w2,
    float* __restrict__ rx6, float* __restrict__ ry6)
{
    __shared__ __align__(16) float2 as2_s[RPEH];   // {A_j, S_j}  4 KB
    __shared__ short w2b_s[8][520];                // W2^T bf16   8.1 KB

    const int bq = blockIdx.x;          // 0..599
    const int axis = blockIdx.y;
    const int l = blockIdx.z;
    const float* __restrict__ w1 = (axis ? cpb2_w1 : cpb1_w1) + (size_t)l * 1024;
    const float* __restrict__ b1 = (axis ? cpb2_b1 : cpb1_b1) + (size_t)l * 512;
    const float* __restrict__ w2 = (axis ? cpb2_w2 : cpb1_w2) + (size_t)l * 4096;
    const float* __restrict__ bx = axis ? boxy : boxx;
    const int t = threadIdx.x;

    const float x0 = bx[bq * 2 + 0], x1 = bx[bq * 2 + 1];

    for (int j = t; j < RPEH; j += 256) {
        float2 wp = *(const float2*)&w1[2 * j];
        as2_s[j] = make_float2(fmaf(wp.x, x0, fmaf(wp.y, x1, b1[j])),
                               wp.x + wp.y);
    }
    {
        int h = t >> 5, j16 = (t & 31) * 16;
        const float* wp = &w2[h * RPEH + j16];
        float4 a = *(const float4*)wp;
        float4 b = *(const float4*)(wp + 4);
        float4 c = *(const float4*)(wp + 8);
        float4 d = *(const float4*)(wp + 12);
        *(short8*)&w2b_s[h][j16]     = pack_bf8(a, b);
        *(short8*)&w2b_s[h][j16 + 8] = pack_bf8(c, d);
    }
    __syncthreads();

    const int lane = t & 63, w = t >> 6;
    const int l15 = lane & 15, lhi8 = (lane >> 4) * 8, lhi4 = (lane >> 4) * 4;
    const float pos_i = ((w * 16 + l15) + 0.5f) * 16.0f;

    f32x4 acc;
#pragma unroll
    for (int r = 0; r < 4; ++r) acc[r] = 0.f;

#pragma unroll 4
    for (int k0 = 0; k0 < RPEH; k0 += 32) {
        const int j0 = k0 + lhi8;
        const float4* ap = (const float4*)&as2_s[j0];
        float4 p0 = ap[0], p1 = ap[1], p2 = ap[2], p3 = ap[3];
        short8 ha;
        ha[0] = f2bf(fmaxf(fmaf(-pos_i, p0.y, p0.x), 0.f));
        ha[1] = f2bf(fmaxf(fmaf(-pos_i, p0.w, p0.z), 0.f));
        ha[2] = f2bf(fmaxf(fmaf(-pos_i, p1.y, p1.x), 0.f));
        ha[3] = f2bf(fmaxf(fmaf(-pos_i, p1.w, p1.z), 0.f));
        ha[4] = f2bf(fmaxf(fmaf(-pos_i, p2.y, p2.x), 0.f));
        ha[5] = f2bf(fmaxf(fmaf(-pos_i, p2.w, p2.z), 0.f));
        ha[6] = f2bf(fmaxf(fmaf(-pos_i, p3.y, p3.x), 0.f));
        ha[7] = f2bf(fmaxf(fmaf(-pos_i, p3.w, p3.z), 0.f));
        short8 wb;
        if (l15 < 8) wb = *(short8*)&w2b_s[l15][j0];
        else { short8 z = {0,0,0,0,0,0,0,0}; wb = z; }
        acc = __builtin_amdgcn_mfma_f32_16x16x32_bf16(ha, wb, acc, 0, 0, 0);
    }

    if (l15 < 8) {
        const int b = bq / NQ, q = bq % NQ;
        float* __restrict__ dst = (axis ? ry6 : rx6) + (size_t)l * 307200;
        float* p = &dst[((size_t)(b * NHEAD + l15) * NQ + q) * 64 + w * 16 + lhi4];
        *(float4*)p = *(float4*)&acc;
    }
}

// ---------------------------------------------------------------------------
// MFMA flash attention, split-KV, bf16 inputs (pre-scaled Q).
// ---------------------------------------------------------------------------
template<int HAS_RPE>
__global__ __launch_bounds__(256) void attn_mfma(
    const ushort_t* __restrict__ Q, int ldq,
    const ushort_t* __restrict__ K, int ldk,
    const ushort_t* __restrict__ V, int ldv,
    int nkeys, int kps,
    const float* __restrict__ RX, const float* __restrict__ RY,
    ushort_t* __restrict__ po, float* __restrict__ pm, float* __restrict__ pl,
    int nsplit)
{
    __shared__ short Q_s[64][40];
    __shared__ short K_s[64][40];
    __shared__ short V_s[32][72];      // transposed: [d][key]
    __shared__ short P_s[4][16][72];   // per-wave P tile [q][key]

    const int t = threadIdx.x;
    const int lane = t & 63, w = t >> 6;
    const int l15 = lane & 15, lhi8 = (lane >> 4) * 8, lhi4 = (lane >> 4) * 4;
    const int bh = blockIdx.y, b = bh >> 3, h = bh & 7;
    const int q0 = blockIdx.x * 64;
    const int sp = blockIdx.z;

    {
        int q = t >> 2, kc = (t & 3) * 8;
        int qi = q0 + q;
        short8 qv = {0,0,0,0,0,0,0,0};
        if (qi < NQ) qv = *(const short8*)&Q[((size_t)(b * NQ + qi)) * ldq + h * HDIM + kc];
        *(short8*)&Q_s[q][kc] = qv;
    }

    float rxv[4][4];
    const float* ryp[4];
    if (HAS_RPE) {
#pragma unroll
        for (int r = 0; r < 4; ++r) {
            int qi = q0 + w * 16 + lhi4 + r;
            int qc = qi < NQ ? qi : NQ - 1;
            const float* rxp = &RX[((size_t)bh * NQ + qc) * 64];
            ryp[r] = &RY[((size_t)bh * NQ + qc) * 64];
#pragma unroll
            for (int nf = 0; nf < 4; ++nf) rxv[r][nf] = rxp[nf * 16 + l15];
        }
    }

    float m_r[4], l_r[4];
    f32x4 oacc[2];
#pragma unroll
    for (int r = 0; r < 4; ++r) { m_r[r] = -1e30f; l_r[r] = 0.f; }
#pragma unroll
    for (int ni = 0; ni < 2; ++ni)
#pragma unroll
        for (int r = 0; r < 4; ++r) oacc[ni][r] = 0.f;

    const int nt = kps >> 6;
    for (int kt = 0; kt < nt; ++kt) {
        const int key0 = sp * kps + (kt << 6);
        __syncthreads();
        {
            int key = t >> 2, kc = (t & 3) * 8;
            int rk = key0 + key;
            int rkc = rk < nkeys ? rk : nkeys - 1;
            short8 kvv = *(const short8*)&K[((size_t)(b * nkeys + rkc)) * ldk + h * HDIM + kc];
            *(short8*)&K_s[key][kc] = kvv;
            short8 vvv = *(const short8*)&V[((size_t)(b * nkeys + rkc)) * ldv + h * HDIM + kc];
#pragma unroll
            for (int j = 0; j < 8; ++j) V_s[kc + j][key] = vvv[j];
        }
        __syncthreads();

        short8 aq = *(short8*)&Q_s[w * 16 + l15][lhi8];
        f32x4 sacc[4];
#pragma unroll
        for (int nf = 0; nf < 4; ++nf) {
#pragma unroll
            for (int r = 0; r < 4; ++r) sacc[nf][r] = 0.f;
            short8 kb = *(short8*)&K_s[nf * 16 + l15][lhi8];
            sacc[nf] = __builtin_amdgcn_mfma_f32_16x16x32_bf16(aq, kb, sacc[nf], 0, 0, 0);
        }

        const int ktg = key0 >> 6;
        const bool kv0 = key0 +      l15 < nkeys;
        const bool kv1 = key0 + 16 + l15 < nkeys;
        const bool kv2 = key0 + 32 + l15 < nkeys;
        const bool kv3 = key0 + 48 + l15 < nkeys;
        float c_r[4];
#pragma unroll
        for (int r = 0; r < 4; ++r) {
            float ryv = HAS_RPE ? ryp[r][ktg] : 0.f;
            float sv0 = sacc[0][r] + ryv, sv1 = sacc[1][r] + ryv;
            float sv2 = sacc[2][r] + ryv, sv3 = sacc[3][r] + ryv;
            if (HAS_RPE) {
                sv0 += rxv[r][0]; sv1 += rxv[r][1];
                sv2 += rxv[r][2]; sv3 += rxv[r][3];
            }
            sv0 = kv0 ? sv0 : -1e30f;
            sv1 = kv1 ? sv1 : -1e30f;
            sv2 = kv2 ? sv2 : -1e30f;
            sv3 = kv3 ? sv3 : -1e30f;
            float tmax = fmaxf(fmaxf(sv0, sv1), fmaxf(sv2, sv3));
#pragma unroll
            for (int mask = 1; mask < 16; mask <<= 1)
                tmax = fmaxf(tmax, __shfl_xor(tmax, mask));
            float mn = fmaxf(m_r[r], tmax);
            float cc = __expf(m_r[r] - mn);
            m_r[r] = mn; c_r[r] = cc;
            float p0 = __expf(sv0 - mn), p1 = __expf(sv1 - mn);
            float p2 = __expf(sv2 - mn), p3 = __expf(sv3 - mn);
            float ps = p0 + p1 + p2 + p3;
#pragma unroll
            for (int mask = 1; mask < 16; mask <<= 1) ps += __shfl_xor(ps, mask);
            l_r[r] = l_r[r] * cc + ps;
            P_s[w][lhi4 + r][     l15] = f2bf(p0);
            P_s[w][lhi4 + r][16 + l15] = f2bf(p1);
            P_s[w][lhi4 + r][32 + l15] = f2bf(p2);
            P_s[w][lhi4 + r][48 + l15] = f2bf(p3);
        }
#pragma unroll
        for (int ni = 0; ni < 2; ++ni)
#pragma unroll
            for (int r = 0; r < 4; ++r) oacc[ni][r] *= c_r[r];

        short8 pa0 = *(short8*)&P_s[w][l15][lhi8];
        short8 pa1 = *(short8*)&P_s[w][l15][32 + lhi8];
#pragma unroll
        for (int ni = 0; ni < 2; ++ni) {
            short8 vb0 = *(short8*)&V_s[ni * 16 + l15][lhi8];
            short8 vb1 = *(short8*)&V_s[ni * 16 + l15][32 + lhi8];
            oacc[ni] = __builtin_amdgcn_mfma_f32_16x16x32_bf16(pa0, vb0, oacc[ni], 0, 0, 0);
            oacc[ni] = __builtin_amdgcn_mfma_f32_16x16x32_bf16(pa1, vb1, oacc[ni], 0, 0, 0);
        }
    }

#pragma unroll
    for (int r = 0; r < 4; ++r) {
        int qi = q0 + w * 16 + lhi4 + r;
        if (qi < NQ) {
            size_t base = ((size_t)(bh * nsplit + sp) * NQ + qi);
            if (l15 == 0) { pm[base] = m_r[r]; pl[base] = l_r[r]; }
            po[base * 32 + l15] = (ushort_t)f2bf(oacc[0][r]);
            po[base * 32 + 16 + l15] = (ushort_t)f2bf(oacc[1][r]);
        }
    }
}

// ---------------------------------------------------------------------------
// Fused split-combine + output projection (N=K=256), bf16 W direct-load.
// ---------------------------------------------------------------------------
__global__ __launch_bounds__(256) void combine_gemm(
    const ushort_t* __restrict__ po, const float* __restrict__ pm,
    const float* __restrict__ pl, int nsplit,
    const ushort_t* __restrict__ W, const float* __restrict__ bias,
    float* __restrict__ C, int M)
{
    __shared__ short A_s2[64][264];
    const int t = threadIdx.x;
    const int m0 = blockIdx.y * 64, n0 = blockIdx.x * 64;

    // phase 1: combine -> A_s2 (bf16)
    {
        int rloc = t >> 2;
        int row = m0 + rloc;
        int dc = (t & 3) * 64;
        if (row < M) {
            int b = row / NQ, q = row % NQ;
#pragma unroll
            for (int hh = 0; hh < 2; ++hh) {
                int h = (dc >> 5) + hh;
                int bh = b * NHEAD + h;
                float Mx = -1e30f;
                for (int s = 0; s < nsplit; ++s)
                    Mx = fmaxf(Mx, pm[(size_t)(bh * nsplit + s) * NQ + q]);
                float L = 0.f;
                float acc1[32];
#pragma unroll
                for (int d = 0; d < 32; ++d) acc1[d] = 0.f;
                for (int s = 0; s < nsplit; ++s) {
                    size_t base = (size_t)(bh * nsplit + s) * NQ + q;
                    float wgt = __expf(pm[base] - Mx);
                    L += pl[base] * wgt;
                    const ushort_t* pp = &po[base * 32];
#pragma unroll
                    for (int d = 0; d < 32; ++d) acc1[d] += bf2f(pp[d]) * wgt;
                }
                float inv = 1.f / L;
#pragma unroll
                for (int d = 0; d < 32; ++d)
                    A_s2[rloc][dc + hh * 32 + d] = f2bf(acc1[d] * inv);
            }
        } else {
#pragma unroll
            for (int d = 0; d < 64; ++d) A_s2[rloc][dc + d] = 0;
        }
    }
    __syncthreads();

    const int lane = t & 63, w = t >> 6;
    const int wr = w >> 1, wc = w & 1;
    const int l15 = lane & 15, lhi8 = (lane >> 4) * 8;
    const ushort_t* wp0 = &W[(size_t)(n0 + wc * 32 + l15) * 256 + lhi8];
    const ushort_t* wp1 = wp0 + 16 * 256;
    f32x4 acc[2][2];
#pragma unroll
    for (int i = 0; i < 2; ++i)
#pragma unroll
        for (int j = 0; j < 2; ++j)
#pragma unroll
            for (int r = 0; r < 4; ++r) acc[i][j][r] = 0.f;

#pragma unroll
    for (int k0 = 0; k0 < 256; k0 += 32) {
        short8 a0 = *(short8*)&A_s2[wr * 32 + l15][k0 + lhi8];
        short8 a1 = *(short8*)&A_s2[wr * 32 + 16 + l15][k0 + lhi8];
        short8 b0 = *(const short8*)(wp0 + k0);
        short8 b1 = *(const short8*)(wp1 + k0);
        acc[0][0] = __builtin_amdgcn_mfma_f32_16x16x32_bf16(a0, b0, acc[0][0], 0, 0, 0);
        acc[0][1] = __builtin_amdgcn_mfma_f32_16x16x32_bf16(a0, b1, acc[0][1], 0, 0, 0);
        acc[1][0] = __builtin_amdgcn_mfma_f32_16x16x32_bf16(a1, b0, acc[1][0], 0, 0, 0);
        acc[1][1] = __builtin_amdgcn_mfma_f32_16x16x32_bf16(a1, b1, acc[1][1], 0, 0, 0);
    }

    const int rowb = m0 + wr * 32 + (lane >> 4) * 4;
    const int colb = n0 + wc * 32 + l15;
#pragma unroll
    for (int ni = 0; ni < 2; ++ni) {
        int col = colb + ni * 16;
        float bv = bias[col];
#pragma unroll
        for (int mi = 0; mi < 2; ++mi)
#pragma unroll
            for (int r = 0; r < 4; ++r) {
                int row = rowb + mi * 16 + r;
                if (row < M)
                    C[(size_t)row * 256 + col] = acc[mi][ni][r] + bv;
            }
    }
}

// ---------------------------------------------------------------------------
extern "C" void kernel_launch(void* const* d_in, const int* in_sizes, int n_in,
                              void* d_out, int out_size, void* d_ws, size_t ws_size,
                              hipStream_t stream)
{
    const float* tgt   = (const float*)d_in[0];
    const float* qpos  = (const float*)d_in[1];
    const float* refp  = (const float*)d_in[2];
    const float* src   = (const float*)d_in[3];
    const float* spe   = (const float*)d_in[4];
    const float* sa_in_w  = (const float*)d_in[6];
    const float* sa_in_b  = (const float*)d_in[7];
    const float* sa_out_w = (const float*)d_in[8];
    const float* sa_out_b = (const float*)d_in[9];
    const float* n1_w  = (const float*)d_in[10];
    const float* n1_b  = (const float*)d_in[11];
    const float* ca_q_w = (const float*)d_in[12];
    const float* ca_q_b = (const float*)d_in[13];
    const float* ca_k_w = (const float*)d_in[14];
    const float* ca_k_b = (const float*)d_in[15];
    const float* ca_v_w = (const float*)d_in[16];
    const float* ca_v_b = (const float*)d_in[17];
    const float* ca_p_w = (const float*)d_in[18];
    const float* ca_p_b = (const float*)d_in[19];
    const float* cpb1_w1 = (const float*)d_in[20];
    const float* cpb1_b1 = (const float*)d_in[21];
    const float* cpb1_w2 = (const float*)d_in[22];
    const float* cpb2_w1 = (const float*)d_in[23];
    const float* cpb2_b1 = (const float*)d_in[24];
    const float* cpb2_w2 = (const float*)d_in[25];
    const float* n2_w = (const float*)d_in[26];
    const float* n2_b = (const float*)d_in[27];
    const float* ffn_w1 = (const float*)d_in[28];
    const float* ffn_b1 = (const float*)d_in[29];
    const float* ffn_w2 = (const float*)d_in[30];
    const float* ffn_b2 = (const float*)d_in[31];
    const float* n3_w = (const float*)d_in[32];
    const float* n3_b = (const float*)d_in[33];

    float* ws  = (float*)d_ws;
    float* outb = ws;                        // 153600
    float* tb   = outb + 153600;             // 153600
    float* rx6  = tb + 153600;               // 6*307200
    float* ry6  = rx6 + 1843200;             // 6*307200
    float* boxx = ry6 + 1843200;             // 1200
    float* boxy = boxx + 1200;               // 1200
    float* pm   = boxy + 1200;               // 76800
    float* pl   = pm + 76800;                // 76800
    ushort_t* u = (ushort_t*)(pl + 76800);
    ushort_t* qkvb   = u;                    // 460800
    ushort_t* qcb    = qkvb + 460800;        // 153600
    ushort_t* ob16   = qcb + 153600;         // 153600
    ushort_t* oq16   = ob16 + 153600;        // 153600
    ushort_t* hbb    = oq16 + 153600;        // 614400
    ushort_t* poh    = hbb + 614400;         // 2457600
    ushort_t* kvb16  = poh + 2457600;        // 2097152
    ushort_t* srcb16 = kvb16 + 2097152;      // 2097152
    ushort_t* Kcb    = srcb16 + 2097152;     // 12582912
    ushort_t* Vcb    = Kcb + 12582912;       // 12582912
    ushort_t* Wseg   = Vcb + 12582912;       // 6291456
    ushort_t* Wsain  = Wseg;                 // 1179648
    ushort_t* Wsaout = Wsain + 1179648;      // 393216
    ushort_t* Wcaq   = Wsaout + 393216;
    ushort_t* Wcak   = Wcaq + 393216;
    ushort_t* Wcav   = Wcak + 393216;
    ushort_t* Wcap   = Wcav + 393216;
    ushort_t* Wff1   = Wcap + 393216;        // 1572864
    ushort_t* Wff2   = Wff1 + 1572864;       // 1572864

    const int M = BB * NQ;            // 600

    prep_kernel<<<8192, 256, 0, stream>>>(src, spe, tgt, qpos, refp,
        kvb16, srcb16, outb, ob16, oq16, boxx, boxy);
    wconv_kernel<<<3072, 256, 0, stream>>>(sa_in_w, sa_out_w, ca_q_w, ca_k_w,
        ca_v_w, ca_p_w, ffn_w1, ffn_w2, Wseg);
    rpe_all<<<dim3(600, 2, 6), 256, 0, stream>>>(boxx, boxy,
        cpb1_w1, cpb1_b1, cpb1_w2, cpb2_w1, cpb2_b1, cpb2_w2, rx6, ry6);
    kv_mega<<<2048, 256, 0, stream>>>(kvb16, srcb16, Wcak, Wcav,
        ca_k_b, ca_v_b, Kcb, Vcb);

    for (int l = 0; l < NLAYER; ++l) {
        // ---- self attention ----
        gemm_direct<1,0><<<dim3(12, 10), 256, 0, stream>>>(
            oq16, ob16, 512, 256, Wsain + (size_t)l * 196608, sa_in_b + (size_t)l * 768,
            qkvb, 768, M, 256, ATTN_SCALE, 256);
        attn_mfma<0><<<dim3(5, 16, 5), 256, 0, stream>>>(
            qkvb, 768, qkvb + 256, 768, qkvb + 512, 768,
            NQ, 64, nullptr, nullptr, poh, pm, pl, 5);
        combine_gemm<<<dim3(4, 10), 256, 0, stream>>>(
            poh, pm, pl, 5, Wsaout + (size_t)l * 65536, sa_out_b + l * 256, tb, M);
        ln_residual<<<150, 256, 0, stream>>>(outb, tb, qpos,
            n1_w + l * 256, n1_b + l * 256, ob16, oq16, M);

        // ---- cross attention ----
        gemm_direct<1,0><<<dim3(4, 10), 256, 0, stream>>>(
            oq16, oq16, 256, 256, Wcaq + (size_t)l * 65536, ca_q_b + l * 256,
            qcb, 256, M, 256, ATTN_SCALE, 256);
        attn_mfma<1><<<dim3(5, 16, 8), 256, 0, stream>>>(
            qcb, 256, Kcb + (size_t)l * 2097152, 256, Vcb + (size_t)l * 2097152, 256,
            NKV, 512, rx6 + (size_t)l * 307200, ry6 + (size_t)l * 307200,
            poh, pm, pl, 8);
        combine_gemm<<<dim3(4, 10), 256, 0, stream>>>(
            poh, pm, pl, 8, Wcap + (size_t)l * 65536, ca_p_b + l * 256, tb, M);
        ln_residual<<<150, 256, 0, stream>>>(outb, tb, qpos,
            n2_w + l * 256, n2_b + l * 256, ob16, oq16, M);

        // ---- FFN ----
        gemm_direct<1,1><<<dim3(16, 10), 256, 0, stream>>>(
            ob16, ob16, 1024, 256, Wff1 + (size_t)l * 262144, ffn_b1 + l * 1024,
            hbb, 1024, M, 256, 1.f, 0);
        gemm_direct<0,0><<<dim3(4, 10), 256, 0, stream>>>(
            hbb, hbb, 256, 1024, Wff2 + (size_t)l * 262144, ffn_b2 + l * 256,
            tb, 256, M, 1024, 1.f, 0);
        ln_residual<<<150, 256, 0, stream>>>(outb, tb, qpos,
            n3_w + l * 256, n3_b + l * 256, ob16, oq16, M);
    }

    hipMemcpyAsync(d_out, outb, (size_t)M * DMODEL * sizeof(float),
                   hipMemcpyDeviceToDevice, stream);
}

// Round 18
// 775.570 us; speedup vs baseline: 1.0082x; 1.0082x over previous
//
#include <hip/hip_runtime.h>
#include <math.h>

#define NQ   300
#define DMODEL 256
#define NHEAD 8
#define HDIM 32
#define BB   2
#define NKV  4096
#define RPEH 512
#define NLAYER 6
#define ATTN_SCALE 0.17677669529663687f  // 1/sqrt(32)

typedef short short8 __attribute__((ext_vector_type(8)));
typedef float f32x4 __attribute__((ext_vector_type(4)));
typedef unsigned short ushort_t;

__device__ __forceinline__ short f2bf(float f) {
    union { float fv; unsigned u; } v; v.fv = f;
    unsigned r = v.u + 0x7FFFu + ((v.u >> 16) & 1u);   // RNE
    return (short)(r >> 16);
}
__device__ __forceinline__ float bf2f(ushort_t u) {
    union { unsigned u; float f; } v; v.u = ((unsigned)u) << 16;
    return v.f;
}
__device__ __forceinline__ short8 pack_bf8(float4 x, float4 y) {
    short8 v;
    v[0] = f2bf(x.x); v[1] = f2bf(x.y); v[2] = f2bf(x.z); v[3] = f2bf(x.w);
    v[4] = f2bf(y.x); v[5] = f2bf(y.y); v[6] = f2bf(y.z); v[7] = f2bf(y.w);
    return v;
}

// ---------------------------------------------------------------------------
// prep: kvb16 = bf16(src+spe); srcb16 = bf16(src); out init (fp32+bf16+q16);
// box corners.
// ---------------------------------------------------------------------------
__global__ __launch_bounds__(256) void prep_kernel(
    const float* __restrict__ src, const float* __restrict__ spe,
    const float* __restrict__ tgt, const float* __restrict__ qpos,
    const float* __restrict__ refp,
    ushort_t* __restrict__ kvb16, ushort_t* __restrict__ srcb16,
    float* __restrict__ outb, ushort_t* __restrict__ ob16,
    ushort_t* __restrict__ oq16,
    float* __restrict__ boxx, float* __restrict__ boxy)
{
    int i = blockIdx.x * 256 + threadIdx.x;
    if (i < BB * NKV * DMODEL) {
        float s = src[i];
        kvb16[i]  = (ushort_t)f2bf(s + spe[i]);
        srcb16[i] = (ushort_t)f2bf(s);
    }
    if (i < BB * NQ * DMODEL) {
        float tv = tgt[i];
        outb[i] = tv;
        ob16[i] = (ushort_t)f2bf(tv);
        oq16[i] = (ushort_t)f2bf(tv + qpos[i]);
    }
    if (i < BB * NQ) {
        float cx = refp[i * 4 + 0], cy = refp[i * 4 + 1];
        float w  = refp[i * 4 + 2], h  = refp[i * 4 + 3];
        boxx[i * 2 + 0] = cx - 0.5f * w;
        boxx[i * 2 + 1] = cx + 0.5f * w;
        boxy[i * 2 + 0] = cy - 0.5f * h;
        boxy[i * 2 + 1] = cy + 0.5f * h;
    }
}

// ---------------------------------------------------------------------------
// wconv: convert all GEMM weights fp32 -> bf16 into one ws region.
// ---------------------------------------------------------------------------
__global__ __launch_bounds__(256) void wconv_kernel(
    const float* __restrict__ sain, const float* __restrict__ saout,
    const float* __restrict__ caq, const float* __restrict__ cak,
    const float* __restrict__ cav, const float* __restrict__ cap,
    const float* __restrict__ f1, const float* __restrict__ f2,
    ushort_t* __restrict__ dst)
{
    size_t i = ((size_t)blockIdx.x * 256 + threadIdx.x) * 8;
    if (i >= 6291456) return;
    const float* s; size_t off;
    if      (i < 1179648) { s = sain;  off = i; }
    else if (i < 1572864) { s = saout; off = i - 1179648; }
    else if (i < 1966080) { s = caq;   off = i - 1572864; }
    else if (i < 2359296) { s = cak;   off = i - 1966080; }
    else if (i < 2752512) { s = cav;   off = i - 2359296; }
    else if (i < 3145728) { s = cap;   off = i - 2752512; }
    else if (i < 4718592) { s = f1;    off = i - 3145728; }
    else                  { s = f2;    off = i - 4718592; }
    float4 x = *(const float4*)&s[off];
    float4 y = *(const float4*)&s[off + 4];
    *(short8*)&dst[i] = pack_bf8(x, y);
}

// ---------------------------------------------------------------------------
// kv_mega (r16-best + unrolled layer loop, first barrier skipped):
// reg-cached A, coalesced-store epilogue, XCD-swizzled 1024 blocks.
// ---------------------------------------------------------------------------
__global__ __launch_bounds__(256) void kv_mega(
    const ushort_t* __restrict__ kvb16, const ushort_t* __restrict__ srcb16,
    const ushort_t* __restrict__ Wk, const ushort_t* __restrict__ Wv,
    const float* __restrict__ kbias, const float* __restrict__ vbias,
    ushort_t* __restrict__ Kcb, ushort_t* __restrict__ Vcb)
{
    __shared__ short C_s[64][72];
    const int t = threadIdx.x;
    const int lane = t & 63, w = t >> 6;
    const int wr = w >> 1, wc = w & 1;
    const int l15 = lane & 15, lhi8 = (lane >> 4) * 8;

    const int wgid = blockIdx.x;
    const int xcd  = wgid & 7;
    const int idx  = wgid >> 3;            // 0..127
    const int n0   = (idx & 3) * 64;
    const int sel  = (idx >> 2) & 1;
    const int m0   = (xcd * 16 + (idx >> 3)) * 64;

    const ushort_t* A  = sel ? srcb16 : kvb16;
    const ushort_t* Wb = sel ? Wv : Wk;
    const float* bb    = sel ? vbias : kbias;
    ushort_t* Cb       = sel ? Vcb : Kcb;

    // load this lane's two A-row slices into registers (64 VGPRs)
    const ushort_t* ap0 = &A[(size_t)(m0 + wr * 32 + l15) * 256 + lhi8];
    const ushort_t* ap1 = ap0 + 16 * 256;
    short8 a0r[8], a1r[8];
#pragma unroll
    for (int k = 0; k < 8; ++k) {
        a0r[k] = *(const short8*)(ap0 + k * 32);
        a1r[k] = *(const short8*)(ap1 + k * 32);
    }

    const int rowl = wr * 32 + (lane >> 4) * 4;

#pragma unroll
    for (int l = 0; l < NLAYER; ++l) {
        const ushort_t* wp0 = &Wb[(size_t)l * 65536 + (size_t)(n0 + wc * 32 + l15) * 256 + lhi8];
        const ushort_t* wp1 = wp0 + 16 * 256;
        f32x4 acc[2][2];
#pragma unroll
        for (int i = 0; i < 2; ++i)
#pragma unroll
            for (int j = 0; j < 2; ++j)
#pragma unroll
                for (int r = 0; r < 4; ++r) acc[i][j][r] = 0.f;
#pragma unroll
        for (int k = 0; k < 8; ++k) {
            short8 b0 = *(const short8*)(wp0 + k * 32);
            short8 b1 = *(const short8*)(wp1 + k * 32);
            acc[0][0] = __builtin_amdgcn_mfma_f32_16x16x32_bf16(a0r[k], b0, acc[0][0], 0, 0, 0);
            acc[0][1] = __builtin_amdgcn_mfma_f32_16x16x32_bf16(a0r[k], b1, acc[0][1], 0, 0, 0);
            acc[1][0] = __builtin_amdgcn_mfma_f32_16x16x32_bf16(a1r[k], b0, acc[1][0], 0, 0, 0);
            acc[1][1] = __builtin_amdgcn_mfma_f32_16x16x32_bf16(a1r[k], b1, acc[1][1], 0, 0, 0);
        }

        const float* bl = bb + l * 256;
        if (l != 0) __syncthreads();   // previous layer's store-pass reads done
#pragma unroll
        for (int ni = 0; ni < 2; ++ni) {
            int cl = wc * 32 + ni * 16 + l15;
            float bv = bl[n0 + cl];
#pragma unroll
            for (int mi = 0; mi < 2; ++mi)
#pragma unroll
                for (int r = 0; r < 4; ++r)
                    C_s[rowl + mi * 16 + r][cl] = f2bf(acc[mi][ni][r] + bv);
        }
        __syncthreads();

        ushort_t* C = Cb + (size_t)l * (BB * NKV * DMODEL);
#pragma unroll
        for (int p = 0; p < 2; ++p) {
            int e = p * 256 + t;
            int row = e >> 3, c8 = (e & 7) * 8;
            *(short8*)&C[(size_t)(m0 + row) * 256 + n0 + c8] =
                *(short8*)&C_s[row][c8];
        }
    }
}

// ---------------------------------------------------------------------------
// gemm_direct: LDS-free bf16 GEMM.
// ---------------------------------------------------------------------------
template<int OUT_BF16, int RELU>
__global__ __launch_bounds__(256) void gemm_direct(
    const ushort_t* __restrict__ A1, const ushort_t* __restrict__ A2, int plimit,
    int lda, const ushort_t* __restrict__ W, const float* __restrict__ bias,
    void* __restrict__ Cv, int ldc, int M, int K, float scale, int slimit)
{
    const int t = threadIdx.x;
    const int lane = t & 63, w = t >> 6;
    const int wr = w >> 1, wc = w & 1;
    const int l15 = lane & 15, lhi8 = (lane >> 4) * 8;
    const int m0 = blockIdx.y * 64, n0 = blockIdx.x * 64;
    const ushort_t* A = (n0 < plimit) ? A1 : A2;

    int r0 = m0 + wr * 32 + l15;      if (r0 > M - 1) r0 = M - 1;
    int r1 = m0 + wr * 32 + 16 + l15; if (r1 > M - 1) r1 = M - 1;
    const ushort_t* ap0 = &A[(size_t)r0 * lda + lhi8];
    const ushort_t* ap1 = &A[(size_t)r1 * lda + lhi8];
    const ushort_t* wp0 = &W[(size_t)(n0 + wc * 32 + l15) * K + lhi8];
    const ushort_t* wp1 = wp0 + (size_t)16 * K;

    f32x4 acc[2][2];
#pragma unroll
    for (int i = 0; i < 2; ++i)
#pragma unroll
        for (int j = 0; j < 2; ++j)
#pragma unroll
            for (int r = 0; r < 4; ++r) acc[i][j][r] = 0.f;

    for (int k0 = 0; k0 < K; k0 += 32) {
        short8 a0 = *(const short8*)(ap0 + k0);
        short8 a1 = *(const short8*)(ap1 + k0);
        short8 b0 = *(const short8*)(wp0 + k0);
        short8 b1 = *(const short8*)(wp1 + k0);
        acc[0][0] = __builtin_amdgcn_mfma_f32_16x16x32_bf16(a0, b0, acc[0][0], 0, 0, 0);
        acc[0][1] = __builtin_amdgcn_mfma_f32_16x16x32_bf16(a0, b1, acc[0][1], 0, 0, 0);
        acc[1][0] = __builtin_amdgcn_mfma_f32_16x16x32_bf16(a1, b0, acc[1][0], 0, 0, 0);
        acc[1][1] = __builtin_amdgcn_mfma_f32_16x16x32_bf16(a1, b1, acc[1][1], 0, 0, 0);
    }

    const int rowb = m0 + wr * 32 + (lane >> 4) * 4;
    const int colb = n0 + wc * 32 + l15;
#pragma unroll
    for (int ni = 0; ni < 2; ++ni) {
        int col = colb + ni * 16;
        float bv = bias[col];
#pragma unroll
        for (int mi = 0; mi < 2; ++mi)
#pragma unroll
            for (int r = 0; r < 4; ++r) {
                int row = rowb + mi * 16 + r;
                if (row < M) {
                    float v = acc[mi][ni][r] + bv;
                    if (col < slimit) v *= scale;
                    if (RELU) v = fmaxf(v, 0.f);
                    if (OUT_BF16)
                        ((ushort_t*)Cv)[(size_t)row * ldc + col] = (ushort_t)f2bf(v);
                    else
                        ((float*)Cv)[(size_t)row * ldc + col] = v;
                }
            }
    }
}

// ---------------------------------------------------------------------------
// LayerNorm(out + t) -> outb fp32, ob16 bf16, oq16 = bf16(out + qpos)
// ---------------------------------------------------------------------------
__global__ __launch_bounds__(256) void ln_residual(
    float* __restrict__ out, const float* __restrict__ tt,
    const float* __restrict__ qpos,
    const float* __restrict__ w, const float* __restrict__ b,
    ushort_t* __restrict__ ob16, ushort_t* __restrict__ oq16, int rows)
{
    const int wid = threadIdx.x >> 6, lane = threadIdx.x & 63;
    const int row = blockIdx.x * 4 + wid;
    if (row >= rows) return;
    const float* orow = out + row * DMODEL;
    const float* trow = tt + row * DMODEL;
    float x[4];
#pragma unroll
    for (int i = 0; i < 4; ++i) x[i] = orow[lane + 64 * i] + trow[lane + 64 * i];
    float s = x[0] + x[1] + x[2] + x[3];
#pragma unroll
    for (int mask = 1; mask < 64; mask <<= 1) s += __shfl_xor(s, mask);
    float mean = s * (1.f / 256.f);
    float vs = 0.f;
#pragma unroll
    for (int i = 0; i < 4; ++i) { float d = x[i] - mean; vs += d * d; }
#pragma unroll
    for (int mask = 1; mask < 64; mask <<= 1) vs += __shfl_xor(vs, mask);
    float r = rsqrtf(vs * (1.f / 256.f) + 1e-5f);
    float* orw = out + row * DMODEL;
#pragma unroll
    for (int i = 0; i < 4; ++i) {
        int c = lane + 64 * i;
        float val = (x[i] - mean) * r * w[c] + b[c];
        orw[c] = val;
        ob16[row * DMODEL + c] = (ushort_t)f2bf(val);
        oq16[row * DMODEL + c] = (ushort_t)f2bf(val + qpos[row * DMODEL + c]);
    }
}

// ---------------------------------------------------------------------------
// RPE MLP via MFMA. Block = one (bq, axis, layer); grid (600, 2, 6).
// ---------------------------------------------------------------------------
__global__ __launch_bounds__(256) void rpe_all(
    const float* __restrict__ boxx, const float* __restrict__ boxy,
    const float* __restrict__ cpb1_w1, const float* __restrict__ cpb1_b1,
    const float* __restrict__ cpb1_w2,
    const float* __restrict__ cpb2_w1, const float* __restrict__ cpb2_b1,
    const float* __restrict__ cpb2_w2,
    float* __restrict__ rx6, float* __restrict__ ry6)
{
    __shared__ __align__(16) float2 as2_s[RPEH];   // {A_j, S_j}  4 KB
    __shared__ short w2b_s[8][520];                // W2^T bf16   8.1 KB

    const int bq = blockIdx.x;          // 0..599
    const int axis = blockIdx.y;
    const int l = blockIdx.z;
    const float* __restrict__ w1 = (axis ? cpb2_w1 : cpb1_w1) + (size_t)l * 1024;
    const float* __restrict__ b1 = (axis ? cpb2_b1 : cpb1_b1) + (size_t)l * 512;
    const float* __restrict__ w2 = (axis ? cpb2_w2 : cpb1_w2) + (size_t)l * 4096;
    const float* __restrict__ bx = axis ? boxy : boxx;
    const int t = threadIdx.x;

    const float x0 = bx[bq * 2 + 0], x1 = bx[bq * 2 + 1];

    for (int j = t; j < RPEH; j += 256) {
        float2 wp = *(const float2*)&w1[2 * j];
        as2_s[j] = make_float2(fmaf(wp.x, x0, fmaf(wp.y, x1, b1[j])),
                               wp.x + wp.y);
    }
    {
        int h = t >> 5, j16 = (t & 31) * 16;
        const float* wp = &w2[h * RPEH + j16];
        float4 a = *(const float4*)wp;
        float4 b = *(const float4*)(wp + 4);
        float4 c = *(const float4*)(wp + 8);
        float4 d = *(const float4*)(wp + 12);
        *(short8*)&w2b_s[h][j16]     = pack_bf8(a, b);
        *(short8*)&w2b_s[h][j16 + 8] = pack_bf8(c, d);
    }
    __syncthreads();

    const int lane = t & 63, w = t >> 6;
    const int l15 = lane & 15, lhi8 = (lane >> 4) * 8, lhi4 = (lane >> 4) * 4;
    const float pos_i = ((w * 16 + l15) + 0.5f) * 16.0f;

    f32x4 acc;
#pragma unroll
    for (int r = 0; r < 4; ++r) acc[r] = 0.f;

#pragma unroll 4
    for (int k0 = 0; k0 < RPEH; k0 += 32) {
        const int j0 = k0 + lhi8;
        const float4* ap = (const float4*)&as2_s[j0];
        float4 p0 = ap[0], p1 = ap[1], p2 = ap[2], p3 = ap[3];
        short8 ha;
        ha[0] = f2bf(fmaxf(fmaf(-pos_i, p0.y, p0.x), 0.f));
        ha[1] = f2bf(fmaxf(fmaf(-pos_i, p0.w, p0.z), 0.f));
        ha[2] = f2bf(fmaxf(fmaf(-pos_i, p1.y, p1.x), 0.f));
        ha[3] = f2bf(fmaxf(fmaf(-pos_i, p1.w, p1.z), 0.f));
        ha[4] = f2bf(fmaxf(fmaf(-pos_i, p2.y, p2.x), 0.f));
        ha[5] = f2bf(fmaxf(fmaf(-pos_i, p2.w, p2.z), 0.f));
        ha[6] = f2bf(fmaxf(fmaf(-pos_i, p3.y, p3.x), 0.f));
        ha[7] = f2bf(fmaxf(fmaf(-pos_i, p3.w, p3.z), 0.f));
        short8 wb;
        if (l15 < 8) wb = *(short8*)&w2b_s[l15][j0];
        else { short8 z = {0,0,0,0,0,0,0,0}; wb = z; }
        acc = __builtin_amdgcn_mfma_f32_16x16x32_bf16(ha, wb, acc, 0, 0, 0);
    }

    if (l15 < 8) {
        const int b = bq / NQ, q = bq % NQ;
        float* __restrict__ dst = (axis ? ry6 : rx6) + (size_t)l * 307200;
        float* p = &dst[((size_t)(b * NHEAD + l15) * NQ + q) * 64 + w * 16 + lhi4];
        *(float4*)p = *(float4*)&acc;
    }
}

// ---------------------------------------------------------------------------
// MFMA flash attention, split-KV, bf16 inputs (pre-scaled Q).
// ---------------------------------------------------------------------------
template<int HAS_RPE>
__global__ __launch_bounds__(256) void attn_mfma(
    const ushort_t* __restrict__ Q, int ldq,
    const ushort_t* __restrict__ K, int ldk,
    const ushort_t* __restrict__ V, int ldv,
    int nkeys, int kps,
    const float* __restrict__ RX, const float* __restrict__ RY,
    ushort_t* __restrict__ po, float* __restrict__ pm, float* __restrict__ pl,
    int nsplit)
{
    __shared__ short Q_s[64][40];
    __shared__ short K_s[64][40];
    __shared__ short V_s[32][72];      // transposed: [d][key]
    __shared__ short P_s[4][16][72];   // per-wave P tile [q][key]

    const int t = threadIdx.x;
    const int lane = t & 63, w = t >> 6;
    const int l15 = lane & 15, lhi8 = (lane >> 4) * 8, lhi4 = (lane >> 4) * 4;
    const int bh = blockIdx.y, b = bh >> 3, h = bh & 7;
    const int q0 = blockIdx.x * 64;
    const int sp = blockIdx.z;

    {
        int q = t >> 2, kc = (t & 3) * 8;
        int qi = q0 + q;
        short8 qv = {0,0,0,0,0,0,0,0};
        if (qi < NQ) qv = *(const short8*)&Q[((size_t)(b * NQ + qi)) * ldq + h * HDIM + kc];
        *(short8*)&Q_s[q][kc] = qv;
    }

    float rxv[4][4];
    const float* ryp[4];
    if (HAS_RPE) {
#pragma unroll
        for (int r = 0; r < 4; ++r) {
            int qi = q0 + w * 16 + lhi4 + r;
            int qc = qi < NQ ? qi : NQ - 1;
            const float* rxp = &RX[((size_t)bh * NQ + qc) * 64];
            ryp[r] = &RY[((size_t)bh * NQ + qc) * 64];
#pragma unroll
            for (int nf = 0; nf < 4; ++nf) rxv[r][nf] = rxp[nf * 16 + l15];
        }
    }

    float m_r[4], l_r[4];
    f32x4 oacc[2];
#pragma unroll
    for (int r = 0; r < 4; ++r) { m_r[r] = -1e30f; l_r[r] = 0.f; }
#pragma unroll
    for (int ni = 0; ni < 2; ++ni)
#pragma unroll
        for (int r = 0; r < 4; ++r) oacc[ni][r] = 0.f;

    const int nt = kps >> 6;
    for (int kt = 0; kt < nt; ++kt) {
        const int key0 = sp * kps + (kt << 6);
        __syncthreads();
        {
            int key = t >> 2, kc = (t & 3) * 8;
            int rk = key0 + key;
            int rkc = rk < nkeys ? rk : nkeys - 1;
            short8 kvv = *(const short8*)&K[((size_t)(b * nkeys + rkc)) * ldk + h * HDIM + kc];
            *(short8*)&K_s[key][kc] = kvv;
            short8 vvv = *(const short8*)&V[((size_t)(b * nkeys + rkc)) * ldv + h * HDIM + kc];
#pragma unroll
            for (int j = 0; j < 8; ++j) V_s[kc + j][key] = vvv[j];
        }
        __syncthreads();

        short8 aq = *(short8*)&Q_s[w * 16 + l15][lhi8];
        f32x4 sacc[4];
#pragma unroll
        for (int nf = 0; nf < 4; ++nf) {
#pragma unroll
            for (int r = 0; r < 4; ++r) sacc[nf][r] = 0.f;
            short8 kb = *(short8*)&K_s[nf * 16 + l15][lhi8];
            sacc[nf] = __builtin_amdgcn_mfma_f32_16x16x32_bf16(aq, kb, sacc[nf], 0, 0, 0);
        }

        const int ktg = key0 >> 6;
        const bool kv0 = key0 +      l15 < nkeys;
        const bool kv1 = key0 + 16 + l15 < nkeys;
        const bool kv2 = key0 + 32 + l15 < nkeys;
        const bool kv3 = key0 + 48 + l15 < nkeys;
        float c_r[4];
#pragma unroll
        for (int r = 0; r < 4; ++r) {
            float ryv = HAS_RPE ? ryp[r][ktg] : 0.f;
            float sv0 = sacc[0][r] + ryv, sv1 = sacc[1][r] + ryv;
            float sv2 = sacc[2][r] + ryv, sv3 = sacc[3][r] + ryv;
            if (HAS_RPE) {
                sv0 += rxv[r][0]; sv1 += rxv[r][1];
                sv2 += rxv[r][2]; sv3 += rxv[r][3];
            }
            sv0 = kv0 ? sv0 : -1e30f;
            sv1 = kv1 ? sv1 : -1e30f;
            sv2 = kv2 ? sv2 : -1e30f;
            sv3 = kv3 ? sv3 : -1e30f;
            float tmax = fmaxf(fmaxf(sv0, sv1), fmaxf(sv2, sv3));
#pragma unroll
            for (int mask = 1; mask < 16; mask <<= 1)
                tmax = fmaxf(tmax, __shfl_xor(tmax, mask));
            float mn = fmaxf(m_r[r], tmax);
            float cc = __expf(m_r[r] - mn);
            m_r[r] = mn; c_r[r] = cc;
            float p0 = __expf(sv0 - mn), p1 = __expf(sv1 - mn);
            float p2 = __expf(sv2 - mn), p3 = __expf(sv3 - mn);
            float ps = p0 + p1 + p2 + p3;
#pragma unroll
            for (int mask = 1; mask < 16; mask <<= 1) ps += __shfl_xor(ps, mask);
            l_r[r] = l_r[r] * cc + ps;
            P_s[w][lhi4 + r][     l15] = f2bf(p0);
            P_s[w][lhi4 + r][16 + l15] = f2bf(p1);
            P_s[w][lhi4 + r][32 + l15] = f2bf(p2);
            P_s[w][lhi4 + r][48 + l15] = f2bf(p3);
        }
#pragma unroll
        for (int ni = 0; ni < 2; ++ni)
#pragma unroll
            for (int r = 0; r < 4; ++r) oacc[ni][r] *= c_r[r];

        short8 pa0 = *(short8*)&P_s[w][l15][lhi8];
        short8 pa1 = *(short8*)&P_s[w][l15][32 + lhi8];
#pragma unroll
        for (int ni = 0; ni < 2; ++ni) {
            short8 vb0 = *(short8*)&V_s[ni * 16 + l15][lhi8];
            short8 vb1 = *(short8*)&V_s[ni * 16 + l15][32 + lhi8];
            oacc[ni] = __builtin_amdgcn_mfma_f32_16x16x32_bf16(pa0, vb0, oacc[ni], 0, 0, 0);
            oacc[ni] = __builtin_amdgcn_mfma_f32_16x16x32_bf16(pa1, vb1, oacc[ni], 0, 0, 0);
        }
    }

#pragma unroll
    for (int r = 0; r < 4; ++r) {
        int qi = q0 + w * 16 + lhi4 + r;
        if (qi < NQ) {
            size_t base = ((size_t)(bh * nsplit + sp) * NQ + qi);
            if (l15 == 0) { pm[base] = m_r[r]; pl[base] = l_r[r]; }
            po[base * 32 + l15] = (ushort_t)f2bf(oacc[0][r]);
            po[base * 32 + 16 + l15] = (ushort_t)f2bf(oacc[1][r]);
        }
    }
}

// ---------------------------------------------------------------------------
// Fused split-combine + output projection (N=K=256), bf16 W direct-load.
// ---------------------------------------------------------------------------
__global__ __launch_bounds__(256) void combine_gemm(
    const ushort_t* __restrict__ po, const float* __restrict__ pm,
    const float* __restrict__ pl, int nsplit,
    const ushort_t* __restrict__ W, const float* __restrict__ bias,
    float* __restrict__ C, int M)
{
    __shared__ short A_s2[64][264];
    const int t = threadIdx.x;
    const int m0 = blockIdx.y * 64, n0 = blockIdx.x * 64;

    // phase 1: combine -> A_s2 (bf16)
    {
        int rloc = t >> 2;
        int row = m0 + rloc;
        int dc = (t & 3) * 64;
        if (row < M) {
            int b = row / NQ, q = row % NQ;
#pragma unroll
            for (int hh = 0; hh < 2; ++hh) {
                int h = (dc >> 5) + hh;
                int bh = b * NHEAD + h;
                float Mx = -1e30f;
                for (int s = 0; s < nsplit; ++s)
                    Mx = fmaxf(Mx, pm[(size_t)(bh * nsplit + s) * NQ + q]);
                float L = 0.f;
                float acc1[32];
#pragma unroll
                for (int d = 0; d < 32; ++d) acc1[d] = 0.f;
                for (int s = 0; s < nsplit; ++s) {
                    size_t base = (size_t)(bh * nsplit + s) * NQ + q;
                    float wgt = __expf(pm[base] - Mx);
                    L += pl[base] * wgt;
                    const ushort_t* pp = &po[base * 32];
#pragma unroll
                    for (int d = 0; d < 32; ++d) acc1[d] += bf2f(pp[d]) * wgt;
                }
                float inv = 1.f / L;
#pragma unroll
                for (int d = 0; d < 32; ++d)
                    A_s2[rloc][dc + hh * 32 + d] = f2bf(acc1[d] * inv);
            }
        } else {
#pragma unroll
            for (int d = 0; d < 64; ++d) A_s2[rloc][dc + d] = 0;
        }
    }
    __syncthreads();

    const int lane = t & 63, w = t >> 6;
    const int wr = w >> 1, wc = w & 1;
    const int l15 = lane & 15, lhi8 = (lane >> 4) * 8;
    const ushort_t* wp0 = &W[(size_t)(n0 + wc * 32 + l15) * 256 + lhi8];
    const ushort_t* wp1 = wp0 + 16 * 256;
    f32x4 acc[2][2];
#pragma unroll
    for (int i = 0; i < 2; ++i)
#pragma unroll
        for (int j = 0; j < 2; ++j)
#pragma unroll
            for (int r = 0; r < 4; ++r) acc[i][j][r] = 0.f;

#pragma unroll
    for (int k0 = 0; k0 < 256; k0 += 32) {
        short8 a0 = *(short8*)&A_s2[wr * 32 + l15][k0 + lhi8];
        short8 a1 = *(short8*)&A_s2[wr * 32 + 16 + l15][k0 + lhi8];
        short8 b0 = *(const short8*)(wp0 + k0);
        short8 b1 = *(const short8*)(wp1 + k0);
        acc[0][0] = __builtin_amdgcn_mfma_f32_16x16x32_bf16(a0, b0, acc[0][0], 0, 0, 0);
        acc[0][1] = __builtin_amdgcn_mfma_f32_16x16x32_bf16(a0, b1, acc[0][1], 0, 0, 0);
        acc[1][0] = __builtin_amdgcn_mfma_f32_16x16x32_bf16(a1, b0, acc[1][0], 0, 0, 0);
        acc[1][1] = __builtin_amdgcn_mfma_f32_16x16x32_bf16(a1, b1, acc[1][1], 0, 0, 0);
    }

    const int rowb = m0 + wr * 32 + (lane >> 4) * 4;
    const int colb = n0 + wc * 32 + l15;
#pragma unroll
    for (int ni = 0; ni < 2; ++ni) {
        int col = colb + ni * 16;
        float bv = bias[col];
#pragma unroll
        for (int mi = 0; mi < 2; ++mi)
#pragma unroll
            for (int r = 0; r < 4; ++r) {
                int row = rowb + mi * 16 + r;
                if (row < M)
                    C[(size_t)row * 256 + col] = acc[mi][ni][r] + bv;
            }
    }
}

// ---------------------------------------------------------------------------
extern "C" void kernel_launch(void* const* d_in, const int* in_sizes, int n_in,
                              void* d_out, int out_size, void* d_ws, size_t ws_size,
                              hipStream_t stream)
{
    const float* tgt   = (const float*)d_in[0];
    const float* qpos  = (const float*)d_in[1];
    const float* refp  = (const float*)d_in[2];
    const float* src   = (const float*)d_in[3];
    const float* spe   = (const float*)d_in[4];
    const float* sa_in_w  = (const float*)d_in[6];
    const float* sa_in_b  = (const float*)d_in[7];
    const float* sa_out_w = (const float*)d_in[8];
    const float* sa_out_b = (const float*)d_in[9];
    const float* n1_w  = (const float*)d_in[10];
    const float* n1_b  = (const float*)d_in[11];
    const float* ca_q_w = (const float*)d_in[12];
    const float* ca_q_b = (const float*)d_in[13];
    const float* ca_k_w = (const float*)d_in[14];
    const float* ca_k_b = (const float*)d_in[15];
    const float* ca_v_w = (const float*)d_in[16];
    const float* ca_v_b = (const float*)d_in[17];
    const float* ca_p_w = (const float*)d_in[18];
    const float* ca_p_b = (const float*)d_in[19];
    const float* cpb1_w1 = (const float*)d_in[20];
    const float* cpb1_b1 = (const float*)d_in[21];
    const float* cpb1_w2 = (const float*)d_in[22];
    const float* cpb2_w1 = (const float*)d_in[23];
    const float* cpb2_b1 = (const float*)d_in[24];
    const float* cpb2_w2 = (const float*)d_in[25];
    const float* n2_w = (const float*)d_in[26];
    const float* n2_b = (const float*)d_in[27];
    const float* ffn_w1 = (const float*)d_in[28];
    const float* ffn_b1 = (const float*)d_in[29];
    const float* ffn_w2 = (const float*)d_in[30];
    const float* ffn_b2 = (const float*)d_in[31];
    const float* n3_w = (const float*)d_in[32];
    const float* n3_b = (const float*)d_in[33];

    float* ws  = (float*)d_ws;
    float* outb = ws;                        // 153600
    float* tb   = outb + 153600;             // 153600
    float* rx6  = tb + 153600;               // 6*307200
    float* ry6  = rx6 + 1843200;             // 6*307200
    float* boxx = ry6 + 1843200;             // 1200
    float* boxy = boxx + 1200;               // 1200
    float* pm   = boxy + 1200;               // 76800
    float* pl   = pm + 76800;                // 76800
    ushort_t* u = (ushort_t*)(pl + 76800);
    ushort_t* qkvb   = u;                    // 460800
    ushort_t* qcb    = qkvb + 460800;        // 153600
    ushort_t* ob16   = qcb + 153600;         // 153600
    ushort_t* oq16   = ob16 + 153600;        // 153600
    ushort_t* hbb    = oq16 + 153600;        // 614400
    ushort_t* poh    = hbb + 614400;         // 2457600
    ushort_t* kvb16  = poh + 2457600;        // 2097152
    ushort_t* srcb16 = kvb16 + 2097152;      // 2097152
    ushort_t* Kcb    = srcb16 + 2097152;     // 12582912
    ushort_t* Vcb    = Kcb + 12582912;       // 12582912
    ushort_t* Wseg   = Vcb + 12582912;       // 6291456
    ushort_t* Wsain  = Wseg;                 // 1179648
    ushort_t* Wsaout = Wsain + 1179648;      // 393216
    ushort_t* Wcaq   = Wsaout + 393216;
    ushort_t* Wcak   = Wcaq + 393216;
    ushort_t* Wcav   = Wcak + 393216;
    ushort_t* Wcap   = Wcav + 393216;
    ushort_t* Wff1   = Wcap + 393216;        // 1572864
    ushort_t* Wff2   = Wff1 + 1572864;       // 1572864

    const int M = BB * NQ;            // 600

    prep_kernel<<<8192, 256, 0, stream>>>(src, spe, tgt, qpos, refp,
        kvb16, srcb16, outb, ob16, oq16, boxx, boxy);
    wconv_kernel<<<3072, 256, 0, stream>>>(sa_in_w, sa_out_w, ca_q_w, ca_k_w,
        ca_v_w, ca_p_w, ffn_w1, ffn_w2, Wseg);
    rpe_all<<<dim3(600, 2, 6), 256, 0, stream>>>(boxx, boxy,
        cpb1_w1, cpb1_b1, cpb1_w2, cpb2_w1, cpb2_b1, cpb2_w2, rx6, ry6);
    kv_mega<<<1024, 256, 0, stream>>>(kvb16, srcb16, Wcak, Wcav,
        ca_k_b, ca_v_b, Kcb, Vcb);

    for (int l = 0; l < NLAYER; ++l) {
        // ---- self attention ----
        gemm_direct<1,0><<<dim3(12, 10), 256, 0, stream>>>(
            oq16, ob16, 512, 256, Wsain + (size_t)l * 196608, sa_in_b + (size_t)l * 768,
            qkvb, 768, M, 256, ATTN_SCALE, 256);
        attn_mfma<0><<<dim3(5, 16, 5), 256, 0, stream>>>(
            qkvb, 768, qkvb + 256, 768, qkvb + 512, 768,
            NQ, 64, nullptr, nullptr, poh, pm, pl, 5);
        combine_gemm<<<dim3(4, 10), 256, 0, stream>>>(
            poh, pm, pl, 5, Wsaout + (size_t)l * 65536, sa_out_b + l * 256, tb, M);
        ln_residual<<<150, 256, 0, stream>>>(outb, tb, qpos,
            n1_w + l * 256, n1_b + l * 256, ob16, oq16, M);

        // ---- cross attention ----
        gemm_direct<1,0><<<dim3(4, 10), 256, 0, stream>>>(
            oq16, oq16, 256, 256, Wcaq + (size_t)l * 65536, ca_q_b + l * 256,
            qcb, 256, M, 256, ATTN_SCALE, 256);
        attn_mfma<1><<<dim3(5, 16, 8), 256, 0, stream>>>(
            qcb, 256, Kcb + (size_t)l * 2097152, 256, Vcb + (size_t)l * 2097152, 256,
            NKV, 512, rx6 + (size_t)l * 307200, ry6 + (size_t)l * 307200,
            poh, pm, pl, 8);
        combine_gemm<<<dim3(4, 10), 256, 0, stream>>>(
            poh, pm, pl, 8, Wcap + (size_t)l * 65536, ca_p_b + l * 256, tb, M);
        ln_residual<<<150, 256, 0, stream>>>(outb, tb, qpos,
            n2_w + l * 256, n2_b + l * 256, ob16, oq16, M);

        // ---- FFN ----
        gemm_direct<1,1><<<dim3(16, 10), 256, 0, stream>>>(
            ob16, ob16, 1024, 256, Wff1 + (size_t)l * 262144, ffn_b1 + l * 1024,
            hbb, 1024, M, 256, 1.f, 0);
        gemm_direct<0,0><<<dim3(4, 10), 256, 0, stream>>>(
            hbb, hbb, 256, 1024, Wff2 + (size_t)l * 262144, ffn_b2 + l * 256,
            tb, 256, M, 1024, 1.f, 0);
        ln_residual<<<150, 256, 0, stream>>>(outb, tb, qpos,
            n3_w + l * 256, n3_b + l * 256, ob16, oq16, M);
    }

    hipMemcpyAsync(d_out, outb, (size_t)M * DMODEL * sizeof(float),
                   hipMemcpyDeviceToDevice, stream);
}